// Round 9
// baseline (205.286 us; speedup 1.0000x reference)
//
#include <hip/hip_runtime.h>

// FactorizedSpectralConv: B=8, S1=S2=256, C=64, M1=M2=32.
// Fused per-dim kernels: truncated DFT (MFMA f16) -> complex mix (MFMA f16)
// -> iDFT (MFMA f16) -> direct fragment stores.
//
// R8->R9: 512thr/4-slab/74KB-LDS (2 blocks/CU, occupancy 21%, all pipes idle)
//   -> 256thr/2-slab/36.9KB-LDS, 1024 blocks, 4 blocks/CU: cross-block phase
//   overlap for the latency-bound regime. Fragment math unchanged.
//
// MFMA mapping discipline: logical k index f(g2,e) = 8*g2 + e used for BOTH
// A (init-built tables) and B (LDS staging layout). C/D layout:
// col = lane&31, row = (reg&3) + 8*(reg>>2) + 4*(lane>>5)  [HW-verified].
// Lessons: R3-R5 write-amp was register spills (keep VGPR budget >= need).

namespace {

constexpr int S = 256, C = 64;
constexpr int NC = 128;            // cols per block (2 slabs x 64 ch)
constexpr int NP = 2;              // slabs per block

typedef _Float16 f16;
typedef _Float16 f16x2 __attribute__((ext_vector_type(2)));
typedef _Float16 f16x4 __attribute__((ext_vector_type(4)));
typedef _Float16 f16x8 __attribute__((ext_vector_type(8)));
typedef float f32x16 __attribute__((ext_vector_type(16)));

// ws layout (float offsets)
constexpr int OFF_FWDF = 0;       // fwd A-frag table: 16384 f16 (8192 fl)
constexpr int OFF_INVF = 8192;    // inv A-frag table: 16384 f16 (8192 fl)
constexpr int OFF_A2   = 16384;   // mix A-frag tables: 2 dims x 524288 f16
// total 540672 floats = 2.16 MB

// LDS geometry: rows of NC col-slots, 16B per col, +16B pad per 8 cols.
constexpr int P2  = NC * 16 + (NC / 8) * 16;   // 2304 B row pitch
constexpr int XFO = 8 * P2;                    // region B (Yt) after region A
constexpr int LDS_BYTES = 16 * P2;             // 36864 B

__device__ __host__ inline int cadr(int c) { return c * 16 + (c >> 3) * 16; }

// ---- init: DFT/iDFT A-fragment tables (f16, k = kk*16 + 8*g2 + e) ----
__global__ void k_init_frag(float* __restrict__ ws) {
  int t = blockIdx.x * 256 + threadIdx.x;  // 0..32767
  f16* fwdF = (f16*)(ws + OFF_FWDF);
  f16* invF = (f16*)(ws + OFF_INVF);
  if (t < 16384) {
    int e = t & 7, lane = (t >> 3) & 63, mtkk = t >> 9;
    int mt = mtkk & 1, kk = mtkk >> 1;
    int mc = mt * 32 + (lane & 31);
    int x = kk * 16 + 8 * (lane >> 5) + e;
    int r = mc >> 1;
    double ang = (double)((r * x) & 255) * (3.14159265358979323846 / 128.0);
    double v = (mc & 1) ? -sin(ang) : cos(ang);
    fwdF[t] = (f16)(float)v;
  } else {
    int t2 = t - 16384;
    int e = t2 & 7, lane = (t2 >> 3) & 63, mtg = (t2 >> 9) & 7, kk = t2 >> 12;
    int u = mtg * 32 + (lane & 31);
    int mcv = kk * 16 + 8 * (lane >> 5) + e;
    int r = mcv >> 1;
    double wgt = (r == 0) ? 1.0 : 2.0;
    double ang = (double)((r * u) & 255) * (3.14159265358979323846 / 128.0);
    double v = (mcv & 1) ? -wgt * sin(ang) : wgt * cos(ang);
    invF[t2] = (f16)(float)(v * (1.0 / 256.0));
  }
}

// ---- init: realified mix A-frag table (per dim) ----
// A2[(((r*4+mt)*8+kk)*64+l)*8+e] = Areal[m = mt*32+(l&31)][kreal = kk*16+8*(l>>5)+e]
// Areal rows m=2i (Yr): [Kr, -Ki]; m=2i+1 (Yi): [Ki, Kr]; cols kreal = 2j+imi.
__global__ void k_init_A2(const float* __restrict__ kr, const float* __restrict__ ki,
                          f16* __restrict__ A2) {
  int t = blockIdx.x * 256 + threadIdx.x;  // 0..524287
  int e = t & 7, l = (t >> 3) & 63, kk = (t >> 9) & 7, mt = (t >> 12) & 3, r = t >> 14;
  int m = mt * 32 + (l & 31);
  int kreal = kk * 16 + 8 * (l >> 5) + e;
  int i = m >> 1, imo = m & 1, j = kreal >> 1, imi = kreal & 1;
  int src = (r * 64 + i) * 64 + j;
  float v = (imi == 0) ? ((imo == 0) ? kr[src] : ki[src])
                       : ((imo == 0) ? -ki[src] : kr[src]);
  A2[t] = (f16)v;
}

// ---- main fused kernel ----
// Block = (b, 2 slabs along the non-transformed axis), 256 threads (4 waves).
template <int DIM>
__launch_bounds__(256, 4)
__global__ void k_dim(const float* __restrict__ X, const float* __restrict__ ws,
                      float* __restrict__ out) {
  __shared__ char sm[LDS_BYTES] __attribute__((aligned(16)));

  const int tid = threadIdx.x;
  const int l = tid & 63, w = tid >> 6;    // wave 0..3
  const int g2 = l >> 5, l31 = l & 31;
  const int n0 = w * 32;                   // wave's 32-col window (0..127)
  const int b = blockIdx.x >> 7;
  const int t2 = (blockIdx.x & 127) * NP;  // first slab
  const size_t bbase = (size_t)b * (S * S * C);
  const f16* fwdF = (const f16*)(ws + OFF_FWDF);
  const f16* invF = (const f16*)(ws + OFF_INVF);
  const f16* A2 = (const f16*)(ws + OFF_A2) + (DIM == 0 ? 0 : 524288);

  auto gofs = [&](int u, int c) -> size_t {
    if (DIM == 0)
      return bbase + (size_t)u * (S * C) + (size_t)(t2 + (c >> 6)) * C + (c & 63);
    else
      return bbase + (size_t)(t2 + (c >> 6)) * (S * C) + (size_t)u * C + (c & 63);
  };

  // staging: wave w owns u-subrows w*8..w*8+7; cols via l and l+64
  const int c1 = l;
  const int c2 = l + 64;

  float r1[8], r2[8];
  auto stage_load = [&](int u0) {
#pragma unroll
    for (int j = 0; j < 8; ++j) r1[j] = X[gofs(u0 + w * 8 + j, c1)];
#pragma unroll
    for (int j = 0; j < 8; ++j) r2[j] = X[gofs(u0 + w * 8 + j, c2)];
  };
  auto stage_write = [&](int buf) {
    f16x8 v1, v2;
#pragma unroll
    for (int j = 0; j < 8; ++j) { v1[j] = (f16)r1[j]; v2[j] = (f16)r2[j]; }
    char* base = sm + buf * (4 * P2) + w * P2;
    *(f16x8*)(base + cadr(c1)) = v1;
    *(f16x8*)(base + cadr(c2)) = v2;
  };

  // ---------------- Phase 1: truncated DFT via MFMA ----------------
  f32x16 acc0, acc1;
#pragma unroll
  for (int q = 0; q < 16; ++q) { acc0[q] = 0.f; acc1[q] = 0.f; }

  stage_load(0);
  stage_write(0);
  __syncthreads();

  for (int ch = 0; ch < 8; ++ch) {
    if (ch < 7) stage_load((ch + 1) * 32);
    const char* bbuf = sm + (ch & 1) * (4 * P2);
#pragma unroll
    for (int ks = 0; ks < 2; ++ks) {
      const int kk = ch * 2 + ks;
      f16x8 bf = *(const f16x8*)(bbuf + (ks * 2 + g2) * P2 + cadr(n0 + l31));
      f16x8 a0 = *(const f16x8*)(fwdF + ((size_t)(kk * 2 + 0) * 64 + l) * 8);
      f16x8 a1 = *(const f16x8*)(fwdF + ((size_t)(kk * 2 + 1) * 64 + l) * 8);
      acc0 = __builtin_amdgcn_mfma_f32_32x32x16_f16(a0, bf, acc0, 0, 0, 0);
      acc1 = __builtin_amdgcn_mfma_f32_32x32x16_f16(a1, bf, acc1, 0, 0, 0);
    }
    if (ch < 7) {
      stage_write((ch + 1) & 1);
      __syncthreads();
    }
  }
  __syncthreads();   // region A (staging) now safe to overwrite with XfB

  // ---------------- Phase 2: acc -> XfB directly (region A, B-frag order) ----
  // Word W = (r*16 + kk*2 + g2p)*NP + p at byte W*16 + (W>>3)*16.
  // acc reg pairs (2t, 2t+1) = (re, im) of mode r.
  {
    const int col = n0 + l31;
    const int p = col >> 6, j = col & 63;
    const int kk = j >> 3, g2p = (j >> 2) & 1, js = j & 3;
#pragma unroll
    for (int pr = 0; pr < 16; ++pr) {
      const int q = (pr & 7) >> 1, hf = pr & 1;
      const int r = 2 * g2 + 4 * q + hf + (pr >> 3) * 16;
      const int reg = 4 * q + 2 * hf;
      const float v0 = (pr < 8) ? acc0[reg] : acc1[reg];
      const float v1 = (pr < 8) ? acc0[reg + 1] : acc1[reg + 1];
      f16x2 v2 = {(f16)v0, (f16)v1};
      const int W = (r * 16 + kk * 2 + g2p) * NP + p;
      *(f16x2*)(sm + W * 16 + (W >> 3) * 16 + js * 4) = v2;
    }
  }
  __syncthreads();

  // ---------------- Phase 3: complex channel mix via MFMA ----------------
  // Wave w: modes r = w*8 + rq (rq = c>>2), mt = c&3. Valid cols l31 < NP.
  {
    const int colsel = l31 & (NP - 1);
#pragma unroll 1
    for (int c = 0; c < 32; ++c) {
      const int rq = c >> 2, mt = c & 3;
      const int r = w * 8 + rq;
      f32x16 acc;
#pragma unroll
      for (int q = 0; q < 16; ++q) acc[q] = 0.f;
#pragma unroll
      for (int kk = 0; kk < 8; ++kk) {
        const int W = (r * 16 + kk * 2 + g2) * NP + colsel;
        f16x8 bf = *(const f16x8*)(sm + W * 16 + (W >> 3) * 16);
        f16x8 af = *(const f16x8*)(A2 + ((size_t)((r * 4 + mt) * 8 + kk) * 64 + l) * 8);
        acc = __builtin_amdgcn_mfma_f32_32x32x16_f16(af, bf, acc, 0, 0, 0);
      }
      if (l31 < NP) {
        char* yb = sm + XFO + (r >> 2) * P2;  // Yt row = mc>>3 = r>>2
        const int ebyte = (rq & 3) * 4;       // byte of (re,im) pair in col-slot
#pragma unroll
        for (int t = 0; t < 8; ++t) {
          int reg = t * 2;
          int rowin = (reg & 3) + 8 * (reg >> 2) + 4 * g2;   // even
          int i = (mt * 32 + rowin) >> 1;
          f16x2 v2 = {(f16)acc[reg], (f16)acc[reg + 1]};
          *(f16x2*)(yb + cadr(l31 * 64 + i) + ebyte) = v2;
        }
      }
    }
  }
  __syncthreads();

  // ---------------- Phase 4: iDFT via MFMA -> direct fragment stores ----
  // No barriers: Yt (region B) is read-only here; waves fully independent.
  const int colg = n0 + l31;
  const int pp = colg >> 6, jj = colg & 63;
#pragma unroll 1
  for (int h = 0; h < 2; ++h) {
#pragma unroll 1
    for (int mt = 0; mt < 4; ++mt) {
      f32x16 a4;
#pragma unroll
      for (int q = 0; q < 16; ++q) a4[q] = 0.f;

#pragma unroll
      for (int kk = 0; kk < 4; ++kk) {
        f16x8 bf = *(const f16x8*)(sm + XFO + (kk * 2 + g2) * P2 + cadr(colg));
        f16x8 A = *(const f16x8*)(invF + ((size_t)(kk * 8 + h * 4 + mt) * 64 + l) * 8);
        a4 = __builtin_amdgcn_mfma_f32_32x32x16_f16(A, bf, a4, 0, 0, 0);
      }

      const int u0 = (h * 4 + mt) * 32;
#pragma unroll
      for (int reg = 0; reg < 16; ++reg) {
        const int u = u0 + (reg & 3) + 8 * (reg >> 2) + 4 * g2;
        size_t g = (DIM == 0)
                       ? bbase + (size_t)u * (S * C) + (size_t)(t2 + pp) * C + jj
                       : bbase + (size_t)(t2 + pp) * (S * C) + (size_t)u * C + jj;
        if (DIM == 0) out[g] = a4[reg];
        else          out[g] += a4[reg];
      }
    }
  }
}

}  // namespace

extern "C" void kernel_launch(void* const* d_in, const int* in_sizes, int n_in,
                              void* d_out, int out_size, void* d_ws, size_t ws_size,
                              hipStream_t stream) {
  (void)in_sizes; (void)n_in; (void)out_size; (void)ws_size;
  const float* X   = (const float*)d_in[0];
  const float* k0r = (const float*)d_in[1];
  const float* k0i = (const float*)d_in[2];
  const float* k1r = (const float*)d_in[3];
  const float* k1i = (const float*)d_in[4];
  float* out = (float*)d_out;
  float* ws  = (float*)d_ws;
  f16* A2 = (f16*)(ws + OFF_A2);

  k_init_frag<<<128, 256, 0, stream>>>(ws);
  k_init_A2<<<2048, 256, 0, stream>>>(k0r, k0i, A2);
  k_init_A2<<<2048, 256, 0, stream>>>(k1r, k1i, A2 + 524288);
  k_dim<0><<<1024, 256, 0, stream>>>(X, ws, out);   // writes out
  k_dim<1><<<1024, 256, 0, stream>>>(X, ws, out);   // accumulates into out
}

// Round 10
// 161.489 us; speedup vs baseline: 1.2712x; 1.2712x over previous
//
#include <hip/hip_runtime.h>

// FactorizedSpectralConv: B=8, S1=S2=256, C=64, M1=M2=32.
// Fused per-dim kernels: truncated DFT (MFMA f16) -> complex mix (MFMA f16)
// -> iDFT (MFMA f16) -> direct fragment stores.
//
// R10 = R8 base (512thr/4-slab/74KB, 512 blocks — R9's 256thr regressed via
// doubled A2 L2 traffic) + register-hoisted B-fragments:
//   phase 3: rq-outer, 8 bf frags in regs, reused across 4 mt  (LDS reads /4)
//   phase 4: 4 bf frags hoisted before (h,mt) loops             (LDS reads /8)
// + single merged init kernel (saves 2 launches).
//
// MFMA mapping discipline: logical k index f(g2,e) = 8*g2 + e used for BOTH
// A (init-built tables) and B (LDS staging layout). C/D layout:
// col = lane&31, row = (reg&3) + 8*(reg>>2) + 4*(lane>>5)  [HW-verified].
// Lessons: R3-R5 write-amp was register spills (keep VGPR budget >= need).

namespace {

constexpr int S = 256, C = 64;

typedef _Float16 f16;
typedef _Float16 f16x2 __attribute__((ext_vector_type(2)));
typedef _Float16 f16x4 __attribute__((ext_vector_type(4)));
typedef _Float16 f16x8 __attribute__((ext_vector_type(8)));
typedef float f32x16 __attribute__((ext_vector_type(16)));

// ws layout (float offsets)
constexpr int OFF_FWDF = 0;       // fwd A-frag table: 16384 f16 (8192 fl)
constexpr int OFF_INVF = 8192;    // inv A-frag table: 16384 f16 (8192 fl)
constexpr int OFF_A2   = 16384;   // mix A-frag tables: 2 dims x 524288 f16
// total 540672 floats = 2.16 MB

// LDS geometry: rows of 256 col-slots, 16B per col, +16B pad per 8 cols.
constexpr int P   = 4624;          // row pitch bytes
constexpr int XFO = 8 * P;         // region B (Yt) after region A (staging/XfB)
constexpr int LDS_BYTES = 16 * P;  // 73984 B

__device__ __host__ inline int cadr(int c) { return c * 16 + (c >> 3) * 16; }

// ---- merged init: DFT/iDFT A-frag tables + both mix A2 tables ----
// grid 4224 x 256: blocks [0,128) -> frag tables; [128,2176) -> A2 dim0;
// [2176,4224) -> A2 dim1.
__global__ void k_init_all(const float* __restrict__ k0r, const float* __restrict__ k0i,
                           const float* __restrict__ k1r, const float* __restrict__ ki1,
                           float* __restrict__ ws) {
  const int bid = blockIdx.x;
  if (bid < 128) {
    int t = bid * 256 + threadIdx.x;  // 0..32767
    f16* fwdF = (f16*)(ws + OFF_FWDF);
    f16* invF = (f16*)(ws + OFF_INVF);
    if (t < 16384) {
      int e = t & 7, lane = (t >> 3) & 63, mtkk = t >> 9;
      int mt = mtkk & 1, kk = mtkk >> 1;
      int mc = mt * 32 + (lane & 31);
      int x = kk * 16 + 8 * (lane >> 5) + e;
      int r = mc >> 1;
      double ang = (double)((r * x) & 255) * (3.14159265358979323846 / 128.0);
      double v = (mc & 1) ? -sin(ang) : cos(ang);
      fwdF[t] = (f16)(float)v;
    } else {
      int t2 = t - 16384;
      int e = t2 & 7, lane = (t2 >> 3) & 63, mtg = (t2 >> 9) & 7, kk = t2 >> 12;
      int u = mtg * 32 + (lane & 31);
      int mcv = kk * 16 + 8 * (lane >> 5) + e;
      int r = mcv >> 1;
      double wgt = (r == 0) ? 1.0 : 2.0;
      double ang = (double)((r * u) & 255) * (3.14159265358979323846 / 128.0);
      double v = (mcv & 1) ? -wgt * sin(ang) : wgt * cos(ang);
      invF[t2] = (f16)(float)(v * (1.0 / 256.0));
    }
    return;
  }
  // A2[(((r*4+mt)*8+kk)*64+l)*8+e] = Areal[m=mt*32+(l&31)][kreal=kk*16+8*(l>>5)+e]
  // rows m=2i: [Kr, -Ki]; m=2i+1: [Ki, Kr]; cols kreal = 2j+imi.
  const int db = bid - 128;
  const float* kr = (db < 2048) ? k0r : k1r;
  const float* ki = (db < 2048) ? k0i : ki1;
  f16* A2 = (f16*)(ws + OFF_A2) + ((db < 2048) ? 0 : 524288);
  int t = (db & 2047) * 256 + threadIdx.x;  // 0..524287
  int e = t & 7, l = (t >> 3) & 63, kk = (t >> 9) & 7, mt = (t >> 12) & 3, r = t >> 14;
  int m = mt * 32 + (l & 31);
  int kreal = kk * 16 + 8 * (l >> 5) + e;
  int i = m >> 1, imo = m & 1, j = kreal >> 1, imi = kreal & 1;
  int src = (r * 64 + i) * 64 + j;
  float v = (imi == 0) ? ((imo == 0) ? kr[src] : ki[src])
                       : ((imo == 0) ? -ki[src] : kr[src]);
  A2[t] = (f16)v;
}

// ---- main fused kernel ----
// Block = (b, 4 slabs along the non-transformed axis), 512 threads (8 waves).
template <int DIM>
__launch_bounds__(512, 2)
__global__ void k_dim(const float* __restrict__ X, const float* __restrict__ ws,
                      float* __restrict__ out) {
  __shared__ char sm[LDS_BYTES] __attribute__((aligned(16)));

  const int tid = threadIdx.x;
  const int l = tid & 63, w = tid >> 6;
  const int g2 = l >> 5, l31 = l & 31;
  const int n0 = w * 32;                   // wave's 32-col window
  const int b = blockIdx.x >> 6;
  const int t4 = (blockIdx.x & 63) * 4;    // first slab
  const size_t bbase = (size_t)b * (S * S * C);
  const f16* fwdF = (const f16*)(ws + OFF_FWDF);
  const f16* invF = (const f16*)(ws + OFF_INVF);
  const f16* A2 = (const f16*)(ws + OFF_A2) + (DIM == 0 ? 0 : 524288);

  auto gofs = [&](int u, int c) -> size_t {
    if (DIM == 0)
      return bbase + (size_t)u * (S * C) + (size_t)(t4 + (c >> 6)) * C + (c & 63);
    else
      return bbase + (size_t)(t4 + (c >> 6)) * (S * C) + (size_t)u * C + (c & 63);
  };

  // staging assignment: wave -> (ug = w>>1 of 4 u-subrows, half = w&1 of col range)
  const int ug = w >> 1;
  const int c1 = (w & 1) * 128 + l;
  const int c2 = c1 + 64;

  float r1[8], r2[8];
  auto stage_load = [&](int u0) {
#pragma unroll
    for (int j = 0; j < 8; ++j) r1[j] = X[gofs(u0 + ug * 8 + j, c1)];
#pragma unroll
    for (int j = 0; j < 8; ++j) r2[j] = X[gofs(u0 + ug * 8 + j, c2)];
  };
  auto stage_write = [&](int buf) {
    f16x8 v1, v2;
#pragma unroll
    for (int j = 0; j < 8; ++j) { v1[j] = (f16)r1[j]; v2[j] = (f16)r2[j]; }
    char* base = sm + buf * (4 * P) + ug * P;
    *(f16x8*)(base + cadr(c1)) = v1;
    *(f16x8*)(base + cadr(c2)) = v2;
  };

  // ---------------- Phase 1: truncated DFT via MFMA ----------------
  f32x16 acc0, acc1;
#pragma unroll
  for (int q = 0; q < 16; ++q) { acc0[q] = 0.f; acc1[q] = 0.f; }

  stage_load(0);
  stage_write(0);
  __syncthreads();

  for (int ch = 0; ch < 8; ++ch) {
    if (ch < 7) stage_load((ch + 1) * 32);
    const char* bbuf = sm + (ch & 1) * (4 * P);
#pragma unroll
    for (int ks = 0; ks < 2; ++ks) {
      const int kk = ch * 2 + ks;
      f16x8 bf = *(const f16x8*)(bbuf + (ks * 2 + g2) * P + cadr(n0 + l31));
      f16x8 a0 = *(const f16x8*)(fwdF + ((size_t)(kk * 2 + 0) * 64 + l) * 8);
      f16x8 a1 = *(const f16x8*)(fwdF + ((size_t)(kk * 2 + 1) * 64 + l) * 8);
      acc0 = __builtin_amdgcn_mfma_f32_32x32x16_f16(a0, bf, acc0, 0, 0, 0);
      acc1 = __builtin_amdgcn_mfma_f32_32x32x16_f16(a1, bf, acc1, 0, 0, 0);
    }
    if (ch < 7) {
      stage_write((ch + 1) & 1);
      __syncthreads();
    }
  }
  __syncthreads();   // region A (staging) now safe to overwrite with XfB

  // ---------------- Phase 2: acc -> XfB directly (region A, B-frag order) ----
  // Word W = (r*16 + kk*2 + g2p)*4 + p at byte W*16 + (W>>3)*16.
  {
    const int col = n0 + l31;
    const int p = col >> 6, j = col & 63;
    const int kk = j >> 3, g2p = (j >> 2) & 1, js = j & 3;
#pragma unroll
    for (int pr = 0; pr < 16; ++pr) {
      const int q = (pr & 7) >> 1, hf = pr & 1;
      const int r = 2 * g2 + 4 * q + hf + (pr >> 3) * 16;
      const int reg = 4 * q + 2 * hf;
      const float v0 = (pr < 8) ? acc0[reg] : acc1[reg];
      const float v1 = (pr < 8) ? acc0[reg + 1] : acc1[reg + 1];
      f16x2 v2 = {(f16)v0, (f16)v1};
      const int W = (r * 16 + kk * 2 + g2p) * 4 + p;
      *(f16x2*)(sm + W * 16 + (W >> 3) * 16 + js * 4) = v2;
    }
  }
  __syncthreads();

  // ---------------- Phase 3: complex channel mix via MFMA ----------------
  // Wave w: modes r = w*4 + rq. bf frags (kk 0..7) hoisted to regs, reused
  // across the 4 mt tiles (cuts phase-3 LDS reads 4x vs mt-outer).
  {
    const int colsel = l31 & 3;
#pragma unroll 1
    for (int rq = 0; rq < 4; ++rq) {
      const int r = w * 4 + rq;
      f16x8 bfr[8];
#pragma unroll
      for (int kk = 0; kk < 8; ++kk) {
        const int W = (r * 16 + kk * 2 + g2) * 4 + colsel;
        bfr[kk] = *(const f16x8*)(sm + W * 16 + (W >> 3) * 16);
      }
      char* yb = sm + XFO + w * P;            // Yt row g3 = r>>2 = w
      const int ebyte = rq * 4;               // e-slot = 2*rq + imo -> byte 4*rq
#pragma unroll 1
      for (int mt = 0; mt < 4; ++mt) {
        f32x16 acc;
#pragma unroll
        for (int q = 0; q < 16; ++q) acc[q] = 0.f;
#pragma unroll
        for (int kk = 0; kk < 8; ++kk) {
          f16x8 af = *(const f16x8*)(A2 + ((size_t)((r * 4 + mt) * 8 + kk) * 64 + l) * 8);
          acc = __builtin_amdgcn_mfma_f32_32x32x16_f16(af, bfr[kk], acc, 0, 0, 0);
        }
        if (l31 < 4) {
#pragma unroll
          for (int t2 = 0; t2 < 8; ++t2) {
            int reg = t2 * 2;
            int rowin = (reg & 3) + 8 * (reg >> 2) + 4 * g2;   // even
            int i = (mt * 32 + rowin) >> 1;
            f16x2 v2 = {(f16)acc[reg], (f16)acc[reg + 1]};
            *(f16x2*)(yb + cadr(l31 * 64 + i) + ebyte) = v2;
          }
        }
      }
    }
  }
  __syncthreads();

  // ---------------- Phase 4: iDFT via MFMA -> direct fragment stores ----
  // bf frags (kk 0..3) hoisted: identical across all 8 (h,mt) tiles.
  const int colg = n0 + l31;
  const int pp = colg >> 6, jj = colg & 63;
  f16x8 bf4[4];
#pragma unroll
  for (int kk = 0; kk < 4; ++kk)
    bf4[kk] = *(const f16x8*)(sm + XFO + (kk * 2 + g2) * P + cadr(colg));

#pragma unroll 1
  for (int h = 0; h < 2; ++h) {
#pragma unroll 1
    for (int mt = 0; mt < 4; ++mt) {
      f32x16 a4;
#pragma unroll
      for (int q = 0; q < 16; ++q) a4[q] = 0.f;

#pragma unroll
      for (int kk = 0; kk < 4; ++kk) {
        f16x8 A = *(const f16x8*)(invF + ((size_t)(kk * 8 + h * 4 + mt) * 64 + l) * 8);
        a4 = __builtin_amdgcn_mfma_f32_32x32x16_f16(A, bf4[kk], a4, 0, 0, 0);
      }

      const int u0 = (h * 4 + mt) * 32;
#pragma unroll
      for (int reg = 0; reg < 16; ++reg) {
        const int u = u0 + (reg & 3) + 8 * (reg >> 2) + 4 * g2;
        size_t g = (DIM == 0)
                       ? bbase + (size_t)u * (S * C) + (size_t)(t4 + pp) * C + jj
                       : bbase + (size_t)(t4 + pp) * (S * C) + (size_t)u * C + jj;
        if (DIM == 0) out[g] = a4[reg];
        else          out[g] += a4[reg];
      }
    }
  }
}

}  // namespace

extern "C" void kernel_launch(void* const* d_in, const int* in_sizes, int n_in,
                              void* d_out, int out_size, void* d_ws, size_t ws_size,
                              hipStream_t stream) {
  (void)in_sizes; (void)n_in; (void)out_size; (void)ws_size;
  const float* X   = (const float*)d_in[0];
  const float* k0r = (const float*)d_in[1];
  const float* k0i = (const float*)d_in[2];
  const float* k1r = (const float*)d_in[3];
  const float* k1i = (const float*)d_in[4];
  float* out = (float*)d_out;
  float* ws  = (float*)d_ws;

  k_init_all<<<4224, 256, 0, stream>>>(k0r, k0i, k1r, k1i, ws);
  k_dim<0><<<512, 512, 0, stream>>>(X, ws, out);   // writes out
  k_dim<1><<<512, 512, 0, stream>>>(X, ws, out);   // accumulates into out
}

// Round 11
// 149.485 us; speedup vs baseline: 1.3733x; 1.0803x over previous
//
#include <hip/hip_runtime.h>

// FactorizedSpectralConv: B=8, S1=S2=256, C=64, M1=M2=32.
// Fused per-dim kernels: truncated DFT (MFMA f16) -> complex mix (MFMA f16)
// -> iDFT (MFMA f16) -> direct fragment stores.
//
// R11 = R10 + traffic cuts:
//   (1) dim0 writes f16 partial to d_ws (67 MB) instead of f32 out (134);
//       dim1 reads partial f16 + writes final f32 once. Fallback to R10's
//       RMW path if ws_size too small (host branch, deterministic).
//   (2) pass-2 block order reversed: first dispatches read the L3-warmest
//       data (X tail + partial tail); X+partial = 201 MB < 256 MB L3.
//   (3) init trig in f32 (f16 rounding dominates; f64 was overhead).
//
// MFMA mapping discipline: logical k index f(g2,e) = 8*g2 + e used for BOTH
// A (init-built tables) and B (LDS staging layout). C/D layout:
// col = lane&31, row = (reg&3) + 8*(reg>>2) + 4*(lane>>5)  [HW-verified].
// Lessons: R3-R5 write-amp was register spills (keep VGPR budget >= need).

namespace {

constexpr int S = 256, C = 64;

typedef _Float16 f16;
typedef _Float16 f16x2 __attribute__((ext_vector_type(2)));
typedef _Float16 f16x4 __attribute__((ext_vector_type(4)));
typedef _Float16 f16x8 __attribute__((ext_vector_type(8)));
typedef float f32x16 __attribute__((ext_vector_type(16)));

// ws layout (float offsets)
constexpr int OFF_FWDF = 0;       // fwd A-frag table: 16384 f16 (8192 fl)
constexpr int OFF_INVF = 8192;    // inv A-frag table: 16384 f16 (8192 fl)
constexpr int OFF_A2   = 16384;   // mix A-frag tables: 2 dims x 524288 f16
constexpr int OFF_PW   = 540672;  // f16 partial (8*256*256*64) -- if ws_size allows
constexpr size_t WS_NEED = (size_t)OFF_PW * 4 + (size_t)8 * 256 * 256 * 64 * 2;

// LDS geometry: rows of 256 col-slots, 16B per col, +16B pad per 8 cols.
constexpr int P   = 4624;          // row pitch bytes
constexpr int XFO = 8 * P;         // region B (Yt) after region A (staging/XfB)
constexpr int LDS_BYTES = 16 * P;  // 73984 B

__device__ __host__ inline int cadr(int c) { return c * 16 + (c >> 3) * 16; }

// ---- merged init: DFT/iDFT A-frag tables + both mix A2 tables ----
__global__ void k_init_all(const float* __restrict__ k0r, const float* __restrict__ k0i,
                           const float* __restrict__ k1r, const float* __restrict__ ki1,
                           float* __restrict__ ws) {
  const int bid = blockIdx.x;
  if (bid < 128) {
    int t = bid * 256 + threadIdx.x;  // 0..32767
    f16* fwdF = (f16*)(ws + OFF_FWDF);
    f16* invF = (f16*)(ws + OFF_INVF);
    if (t < 16384) {
      int e = t & 7, lane = (t >> 3) & 63, mtkk = t >> 9;
      int mt = mtkk & 1, kk = mtkk >> 1;
      int mc = mt * 32 + (lane & 31);
      int x = kk * 16 + 8 * (lane >> 5) + e;
      int r = mc >> 1;
      float ang = (float)((r * x) & 255) * (3.14159265358979323846f / 128.0f);
      float v = (mc & 1) ? -sinf(ang) : cosf(ang);
      fwdF[t] = (f16)v;
    } else {
      int t2 = t - 16384;
      int e = t2 & 7, lane = (t2 >> 3) & 63, mtg = (t2 >> 9) & 7, kk = t2 >> 12;
      int u = mtg * 32 + (lane & 31);
      int mcv = kk * 16 + 8 * (lane >> 5) + e;
      int r = mcv >> 1;
      float wgt = (r == 0) ? 1.0f : 2.0f;
      float ang = (float)((r * u) & 255) * (3.14159265358979323846f / 128.0f);
      float v = (mcv & 1) ? -wgt * sinf(ang) : wgt * cosf(ang);
      invF[t2] = (f16)(v * (1.0f / 256.0f));
    }
    return;
  }
  // A2[(((r*4+mt)*8+kk)*64+l)*8+e] = Areal[m=mt*32+(l&31)][kreal=kk*16+8*(l>>5)+e]
  const int db = bid - 128;
  const float* kr = (db < 2048) ? k0r : k1r;
  const float* ki = (db < 2048) ? k0i : ki1;
  f16* A2 = (f16*)(ws + OFF_A2) + ((db < 2048) ? 0 : 524288);
  int t = (db & 2047) * 256 + threadIdx.x;  // 0..524287
  int e = t & 7, l = (t >> 3) & 63, kk = (t >> 9) & 7, mt = (t >> 12) & 3, r = t >> 14;
  int m = mt * 32 + (l & 31);
  int kreal = kk * 16 + 8 * (l >> 5) + e;
  int i = m >> 1, imo = m & 1, j = kreal >> 1, imi = kreal & 1;
  int src = (r * 64 + i) * 64 + j;
  float v = (imi == 0) ? ((imo == 0) ? kr[src] : ki[src])
                       : ((imo == 0) ? -ki[src] : kr[src]);
  A2[t] = (f16)v;
}

// ---- main fused kernel ----
// MODE 0: DIM0 -> out f32      MODE 1: DIM1, out += (f32 RMW)
// MODE 2: DIM0 -> pw f16       MODE 3: DIM1, out = a4 + pw
template <int MODE>
__launch_bounds__(512, 2)
__global__ void k_dim(const float* __restrict__ X, const float* __restrict__ ws,
                      float* __restrict__ out, f16* __restrict__ pw) {
  constexpr int DIM = (MODE == 0 || MODE == 2) ? 0 : 1;
  __shared__ char sm[LDS_BYTES] __attribute__((aligned(16)));

  const int tid = threadIdx.x;
  const int l = tid & 63, w = tid >> 6;
  const int g2 = l >> 5, l31 = l & 31;
  const int n0 = w * 32;                   // wave's 32-col window
  // pass-2 runs in reversed logical order for L3 temporal locality
  const int bid = (DIM == 1) ? (int)(gridDim.x - 1 - blockIdx.x) : (int)blockIdx.x;
  const int b = bid >> 6;
  const int t4 = (bid & 63) * 4;           // first slab
  const size_t bbase = (size_t)b * (S * S * C);
  const f16* fwdF = (const f16*)(ws + OFF_FWDF);
  const f16* invF = (const f16*)(ws + OFF_INVF);
  const f16* A2 = (const f16*)(ws + OFF_A2) + (DIM == 0 ? 0 : 524288);

  auto gofs = [&](int u, int c) -> size_t {
    if (DIM == 0)
      return bbase + (size_t)u * (S * C) + (size_t)(t4 + (c >> 6)) * C + (c & 63);
    else
      return bbase + (size_t)(t4 + (c >> 6)) * (S * C) + (size_t)u * C + (c & 63);
  };

  // staging assignment: wave -> (ug = w>>1 of 4 u-subrows, half = w&1 of col range)
  const int ug = w >> 1;
  const int c1 = (w & 1) * 128 + l;
  const int c2 = c1 + 64;

  float r1[8], r2[8];
  auto stage_load = [&](int u0) {
#pragma unroll
    for (int j = 0; j < 8; ++j) r1[j] = X[gofs(u0 + ug * 8 + j, c1)];
#pragma unroll
    for (int j = 0; j < 8; ++j) r2[j] = X[gofs(u0 + ug * 8 + j, c2)];
  };
  auto stage_write = [&](int buf) {
    f16x8 v1, v2;
#pragma unroll
    for (int j = 0; j < 8; ++j) { v1[j] = (f16)r1[j]; v2[j] = (f16)r2[j]; }
    char* base = sm + buf * (4 * P) + ug * P;
    *(f16x8*)(base + cadr(c1)) = v1;
    *(f16x8*)(base + cadr(c2)) = v2;
  };

  // ---------------- Phase 1: truncated DFT via MFMA ----------------
  f32x16 acc0, acc1;
#pragma unroll
  for (int q = 0; q < 16; ++q) { acc0[q] = 0.f; acc1[q] = 0.f; }

  stage_load(0);
  stage_write(0);
  __syncthreads();

  for (int ch = 0; ch < 8; ++ch) {
    if (ch < 7) stage_load((ch + 1) * 32);
    const char* bbuf = sm + (ch & 1) * (4 * P);
#pragma unroll
    for (int ks = 0; ks < 2; ++ks) {
      const int kk = ch * 2 + ks;
      f16x8 bf = *(const f16x8*)(bbuf + (ks * 2 + g2) * P + cadr(n0 + l31));
      f16x8 a0 = *(const f16x8*)(fwdF + ((size_t)(kk * 2 + 0) * 64 + l) * 8);
      f16x8 a1 = *(const f16x8*)(fwdF + ((size_t)(kk * 2 + 1) * 64 + l) * 8);
      acc0 = __builtin_amdgcn_mfma_f32_32x32x16_f16(a0, bf, acc0, 0, 0, 0);
      acc1 = __builtin_amdgcn_mfma_f32_32x32x16_f16(a1, bf, acc1, 0, 0, 0);
    }
    if (ch < 7) {
      stage_write((ch + 1) & 1);
      __syncthreads();
    }
  }
  __syncthreads();   // region A (staging) now safe to overwrite with XfB

  // ---------------- Phase 2: acc -> XfB directly (region A, B-frag order) ----
  {
    const int col = n0 + l31;
    const int p = col >> 6, j = col & 63;
    const int kk = j >> 3, g2p = (j >> 2) & 1, js = j & 3;
#pragma unroll
    for (int pr = 0; pr < 16; ++pr) {
      const int q = (pr & 7) >> 1, hf = pr & 1;
      const int r = 2 * g2 + 4 * q + hf + (pr >> 3) * 16;
      const int reg = 4 * q + 2 * hf;
      const float v0 = (pr < 8) ? acc0[reg] : acc1[reg];
      const float v1 = (pr < 8) ? acc0[reg + 1] : acc1[reg + 1];
      f16x2 v2 = {(f16)v0, (f16)v1};
      const int W = (r * 16 + kk * 2 + g2p) * 4 + p;
      *(f16x2*)(sm + W * 16 + (W >> 3) * 16 + js * 4) = v2;
    }
  }
  __syncthreads();

  // ---------------- Phase 3: complex channel mix via MFMA ----------------
  {
    const int colsel = l31 & 3;
#pragma unroll 1
    for (int rq = 0; rq < 4; ++rq) {
      const int r = w * 4 + rq;
      f16x8 bfr[8];
#pragma unroll
      for (int kk = 0; kk < 8; ++kk) {
        const int W = (r * 16 + kk * 2 + g2) * 4 + colsel;
        bfr[kk] = *(const f16x8*)(sm + W * 16 + (W >> 3) * 16);
      }
      char* yb = sm + XFO + w * P;            // Yt row g3 = r>>2 = w
      const int ebyte = rq * 4;
#pragma unroll 1
      for (int mt = 0; mt < 4; ++mt) {
        f32x16 acc;
#pragma unroll
        for (int q = 0; q < 16; ++q) acc[q] = 0.f;
#pragma unroll
        for (int kk = 0; kk < 8; ++kk) {
          f16x8 af = *(const f16x8*)(A2 + ((size_t)((r * 4 + mt) * 8 + kk) * 64 + l) * 8);
          acc = __builtin_amdgcn_mfma_f32_32x32x16_f16(af, bfr[kk], acc, 0, 0, 0);
        }
        if (l31 < 4) {
#pragma unroll
          for (int t2 = 0; t2 < 8; ++t2) {
            int reg = t2 * 2;
            int rowin = (reg & 3) + 8 * (reg >> 2) + 4 * g2;   // even
            int i = (mt * 32 + rowin) >> 1;
            f16x2 v2 = {(f16)acc[reg], (f16)acc[reg + 1]};
            *(f16x2*)(yb + cadr(l31 * 64 + i) + ebyte) = v2;
          }
        }
      }
    }
  }
  __syncthreads();

  // ---------------- Phase 4: iDFT via MFMA -> direct fragment stores ----
  const int colg = n0 + l31;
  const int pp = colg >> 6, jj = colg & 63;
  f16x8 bf4[4];
#pragma unroll
  for (int kk = 0; kk < 4; ++kk)
    bf4[kk] = *(const f16x8*)(sm + XFO + (kk * 2 + g2) * P + cadr(colg));

#pragma unroll 1
  for (int h = 0; h < 2; ++h) {
#pragma unroll 1
    for (int mt = 0; mt < 4; ++mt) {
      f32x16 a4;
#pragma unroll
      for (int q = 0; q < 16; ++q) a4[q] = 0.f;

#pragma unroll
      for (int kk = 0; kk < 4; ++kk) {
        f16x8 A = *(const f16x8*)(invF + ((size_t)(kk * 8 + h * 4 + mt) * 64 + l) * 8);
        a4 = __builtin_amdgcn_mfma_f32_32x32x16_f16(A, bf4[kk], a4, 0, 0, 0);
      }

      const int u0 = (h * 4 + mt) * 32;
#pragma unroll
      for (int reg = 0; reg < 16; ++reg) {
        const int u = u0 + (reg & 3) + 8 * (reg >> 2) + 4 * g2;
        size_t g = (DIM == 0)
                       ? bbase + (size_t)u * (S * C) + (size_t)(t4 + pp) * C + jj
                       : bbase + (size_t)(t4 + pp) * (S * C) + (size_t)u * C + jj;
        if (MODE == 0) out[g] = a4[reg];
        else if (MODE == 1) out[g] += a4[reg];
        else if (MODE == 2) pw[g] = (f16)a4[reg];
        else out[g] = a4[reg] + (float)pw[g];
      }
    }
  }
}

}  // namespace

extern "C" void kernel_launch(void* const* d_in, const int* in_sizes, int n_in,
                              void* d_out, int out_size, void* d_ws, size_t ws_size,
                              hipStream_t stream) {
  (void)in_sizes; (void)n_in; (void)out_size;
  const float* X   = (const float*)d_in[0];
  const float* k0r = (const float*)d_in[1];
  const float* k0i = (const float*)d_in[2];
  const float* k1r = (const float*)d_in[3];
  const float* k1i = (const float*)d_in[4];
  float* out = (float*)d_out;
  float* ws  = (float*)d_ws;
  f16* pw = (f16*)(ws + OFF_PW);

  k_init_all<<<4224, 256, 0, stream>>>(k0r, k0i, k1r, k1i, ws);
  if (ws_size >= WS_NEED) {
    k_dim<2><<<512, 512, 0, stream>>>(X, ws, out, pw);   // dim0 -> f16 partial
    k_dim<3><<<512, 512, 0, stream>>>(X, ws, out, pw);   // dim1 + partial -> out
  } else {
    k_dim<0><<<512, 512, 0, stream>>>(X, ws, out, nullptr);
    k_dim<1><<<512, 512, 0, stream>>>(X, ws, out, nullptr);
  }
}